// Round 5
// baseline (5054.073 us; speedup 1.0000x reference)
//
#include <hip/hip_runtime.h>
#include <hip/hip_bf16.h>
#include <math.h>

// Problem constants (fixed by setup_inputs)
#define NN     65536
#define NE     262144
#define HIDN   256
#define EDIM   64
#define NHEAD  8
#define HDIM   32
#define FFN    1024
#define ASTART 8192
#define NACT   (NN - ASTART)   // 57344
#define ECH    32768           // edge chunk (8 chunks)
#define RCH    32768           // FFN row chunk (2 chunks)

typedef __attribute__((ext_vector_type(8))) short short8;
typedef __attribute__((ext_vector_type(4))) short short4v;
typedef __attribute__((ext_vector_type(4))) float float4v;
typedef __hip_bfloat16 bf16;

__device__ __forceinline__ float b2f(short s) {
    union { unsigned u; float f; } c;
    c.u = ((unsigned)(unsigned short)s) << 16;
    return c.f;
}
__device__ __forceinline__ short f2b(float f) {
    __hip_bfloat16 h = __float2bfloat16(f);
    return *reinterpret_cast<short*>(&h);
}
// dtype-agnostic element load: flag=1 -> fp32 input, flag=0 -> bf16 input
__device__ __forceinline__ float ldf(const void* base, size_t ei, unsigned fl) {
    return fl ? ((const float*)base)[ei] : b2f(((const short*)base)[ei]);
}

__device__ __forceinline__ float gelu_exact(float v) {
    return 0.5f * v * (1.0f + erff(v * 0.70710678118654752f));
}

// Detect input dtype: read first 4096 shorts of x as bf16. Genuine bf16
// N(0,1): ~0 outliers. fp32 misread: ~45% of shorts are log-uniform garbage.
__global__ void detect_kernel(const void* x, unsigned* flag) {
    const short* p = (const short*)x;
    const int lane = threadIdx.x;   // 64 threads
    int c = 0;
    for (int i = 0; i < 64; ++i) {
        float v = fabsf(b2f(p[lane * 64 + i]));
        if (v > 100.f || (v != 0.f && v < 1e-5f)) ++c;
    }
    #pragma unroll
    for (int m = 1; m < 64; m <<= 1) c += __shfl_xor(c, m);
    if (lane == 0) *flag = (c > 256) ? 1u : 0u;
}

// canonical bf16 convert (flag-aware), element offset eoff into src
__global__ void convert_kernel(const void* __restrict__ src, size_t eoff,
                               bf16* __restrict__ dst, int n,
                               const unsigned* __restrict__ flagp) {
    const unsigned fl = *flagp;
    int i = blockIdx.x * 256 + threadIdx.x;
    if (i < n) dst[i] = __float2bfloat16(ldf(src, eoff + i, fl));
}

// dst[C x R] = src[R x C]^T  (flag-aware read, canonical bf16 out)
__global__ void transpose_kernel(const void* __restrict__ src, size_t eoff,
                                 bf16* __restrict__ dst, int R, int Cc,
                                 const unsigned* __restrict__ flagp) {
    const unsigned fl = *flagp;
    int idx = blockIdx.x * 256 + threadIdx.x;
    if (idx >= R * Cc) return;
    int r = idx / Cc, c = idx - r * Cc;
    dst[(size_t)c * R + r] = __float2bfloat16(ldf(src, (size_t)eoff + idx, fl));
}

// ---------------------------------------------------------------------------
// MFMA GEMM: C[M,N] = A[M,K] @ B[K,N] (+bias) (+gelu)
// AMODE: 0 = canonical bf16 A; 1 = fp32 A; 2 = raw input A (flag-dependent).
// BT: canonical bf16, N x K (B transposed); C: bf16 row-major.
// Block = 256 thr = 4 waves; tile 64(M) x 64(N). M%64==0, N%64==0, K%32==0.
// ---------------------------------------------------------------------------
template<int AMODE, bool DO_GELU>
__global__ __launch_bounds__(256) void gemm_kernel(
    const void* __restrict__ A, size_t a_eoff,
    const bf16* __restrict__ BT,
    const bf16* __restrict__ bias,   // length N or nullptr
    bf16* __restrict__ C,
    int M, int Nn, int K,
    const unsigned* __restrict__ flagp)
{
    unsigned fl = 0;
    if (AMODE == 2) fl = *flagp;
    const int bm   = blockIdx.y * 64;
    const int bn   = blockIdx.x * 64;
    const int wave = threadIdx.x >> 6;
    const int lane = threadIdx.x & 63;
    const int l15  = lane & 15;
    const int quad = lane >> 4;
    const int col  = bn + wave * 16 + l15;

    const size_t abase = a_eoff + (size_t)(bm + l15) * K + quad * 8;
    const short* bptr  = (const short*)BT + (size_t)col * K + quad * 8;
    const size_t rstep = (size_t)16 * K;

    float4v acc[4];
    #pragma unroll
    for (int i = 0; i < 4; ++i) acc[i] = (float4v){0.f, 0.f, 0.f, 0.f};

    for (int k0 = 0; k0 < K; k0 += 32) {
        short8 bfrag = *(const short8*)(bptr + k0);
        #pragma unroll
        for (int i = 0; i < 4; ++i) {
            const size_t ae = abase + (size_t)i * rstep + k0;
            short8 afrag;
            if (AMODE == 1 || (AMODE == 2 && fl)) {
                const float* af = (const float*)A + ae;
                float4v f0 = *(const float4v*)af;
                float4v f1 = *(const float4v*)(af + 4);
                #pragma unroll
                for (int j = 0; j < 4; ++j) { afrag[j] = f2b(f0[j]); afrag[4+j] = f2b(f1[j]); }
            } else {
                afrag = *(const short8*)((const short*)A + ae);
            }
            acc[i] = __builtin_amdgcn_mfma_f32_16x16x32_bf16(afrag, bfrag, acc[i], 0, 0, 0);
        }
    }

    const float bv = bias ? b2f(((const short*)bias)[col]) : 0.0f;
    #pragma unroll
    for (int i = 0; i < 4; ++i) {
        const int row0 = bm + i * 16 + quad * 4;
        #pragma unroll
        for (int r = 0; r < 4; ++r) {
            float v = acc[i][r] + bv;
            if (DO_GELU) v = gelu_exact(v);
            C[(size_t)(row0 + r) * Nn + col] = __float2bfloat16(v);
        }
    }
}

// One wave per edge: pe = exp(clamp(score)) (shift-free softmax; scores O(1)).
// lane covers channels [lane*4, lane*4+4); head = lane>>3.
__global__ __launch_bounds__(256) void score_kernel(
    const bf16* __restrict__ q, const bf16* __restrict__ k,
    const bf16* __restrict__ eK,              // chunk-local, ECH x 256
    const int* __restrict__ srcIdx, const int* __restrict__ dstIdx,
    float* __restrict__ pbuf, float* __restrict__ denom, int e0)
{
    const int el = blockIdx.x * 4 + (threadIdx.x >> 6);
    const int e  = e0 + el;
    const int lane = threadIdx.x & 63;
    const int s = srcIdx[e], d = dstIdx[e];
    const int off = lane * 4;

    const short4v qv = *(const short4v*)((const short*)q  + (size_t)d  * HIDN + off);
    const short4v kv = *(const short4v*)((const short*)k  + (size_t)s  * HIDN + off);
    const short4v ev = *(const short4v*)((const short*)eK + (size_t)el * HIDN + off);
    float p = 0.f;
    #pragma unroll
    for (int j = 0; j < 4; ++j) p += b2f(qv[j]) * (b2f(kv[j]) + b2f(ev[j]));
    p += __shfl_xor(p, 1);
    p += __shfl_xor(p, 2);
    p += __shfl_xor(p, 4);
    if ((lane & 7) == 0) {
        const int h = lane >> 3;
        const float sc = fminf(fmaxf(p * 0.17677669529663689f, -30.f), 30.f);
        const float pe = expf(sc);
        pbuf[(size_t)e * NHEAD + h] = pe;
        atomicAdd(&denom[(size_t)d * NHEAD + h], pe);
    }
}

// One wave per edge: agg[dst, c] += alpha[h(c)] * (v[src, c] + eV[e, c])
__global__ __launch_bounds__(256) void agg_kernel(
    const float* __restrict__ p, const float* __restrict__ denom,
    const bf16* __restrict__ v, const bf16* __restrict__ eV,   // eV chunk-local
    const int* __restrict__ srcIdx, const int* __restrict__ dstIdx,
    float* __restrict__ agg, int e0)
{
    const int el = blockIdx.x * 4 + (threadIdx.x >> 6);
    const int e  = e0 + el;
    const int lane = threadIdx.x & 63;
    const int s = srcIdx[e], d = dstIdx[e];
    const int h = lane >> 3;
    const float alpha = p[(size_t)e * NHEAD + h] /
                        fmaxf(denom[(size_t)d * NHEAD + h], 1e-37f);
    const int off = lane * 4;
    const short4v vv = *(const short4v*)((const short*)v  + (size_t)s  * HIDN + off);
    const short4v ev = *(const short4v*)((const short*)eV + (size_t)el * HIDN + off);
    float* ao = agg + (size_t)d * HIDN + off;
    #pragma unroll
    for (int j = 0; j < 4; ++j) atomicAdd(ao + j, alpha * (b2f(vv[j]) + b2f(ev[j])));
}

// One wave per row r in [r0, ...): x = LN(x + t)*s + b (in place, bf16).
__global__ __launch_bounds__(256) void ln_kernel(
    bf16* __restrict__ x, const bf16* __restrict__ t,
    const bf16* __restrict__ sc, const bf16* __restrict__ bi, int r0)
{
    const int row = r0 + blockIdx.x * 4 + (threadIdx.x >> 6);
    const int lane = threadIdx.x & 63;
    const size_t base = (size_t)row * HIDN + lane * 4;
    const size_t tbase = (size_t)(row - r0) * HIDN + lane * 4;
    const short4v xv = *(const short4v*)((const short*)x + base);
    const short4v tv = *(const short4v*)((const short*)t + tbase);
    float v[4];
    #pragma unroll
    for (int j = 0; j < 4; ++j) v[j] = b2f(xv[j]) + b2f(tv[j]);
    float sum = v[0] + v[1] + v[2] + v[3];
    float ssq = v[0]*v[0] + v[1]*v[1] + v[2]*v[2] + v[3]*v[3];
    #pragma unroll
    for (int m = 1; m < 64; m <<= 1) { sum += __shfl_xor(sum, m); ssq += __shfl_xor(ssq, m); }
    const float mean = sum * (1.0f / 256.0f);
    const float var  = fmaxf(ssq * (1.0f / 256.0f) - mean * mean, 0.0f);
    const float rstd = rsqrtf(var + 1e-5f);
    const short4v sv = *(const short4v*)((const short*)sc + lane * 4);
    const short4v bv = *(const short4v*)((const short*)bi + lane * 4);
    short4v out;
    #pragma unroll
    for (int j = 0; j < 4; ++j)
        out[j] = f2b((v[j] - mean) * rstd * b2f(sv[j]) + b2f(bv[j]));
    *(short4v*)((short*)x + base) = out;
}

// One wave per row: out[row, 0..6] = h1[row,:] @ w2 + b2   (w2T is 7 x 256)
// Output dtype follows detected input dtype: flag=1 -> fp32, flag=0 -> bf16.
__global__ __launch_bounds__(256) void head2_kernel(
    const bf16* __restrict__ h1, const bf16* __restrict__ w2T,
    const bf16* __restrict__ b2, void* __restrict__ out,
    const unsigned* __restrict__ flagp)
{
    const unsigned fl = *flagp;
    const int row = blockIdx.x * 4 + (threadIdx.x >> 6);
    const int lane = threadIdx.x & 63;
    const int off = lane * 4;
    const short4v hv = *(const short4v*)((const short*)h1 + (size_t)row * HIDN + off);
    float hf[4];
    #pragma unroll
    for (int j = 0; j < 4; ++j) hf[j] = b2f(hv[j]);
    float acc[7];
    #pragma unroll
    for (int jc = 0; jc < 7; ++jc) {
        const short4v wv = *(const short4v*)((const short*)w2T + jc * HIDN + off);
        float a = hf[0]*b2f(wv[0]) + hf[1]*b2f(wv[1]) + hf[2]*b2f(wv[2]) + hf[3]*b2f(wv[3]);
        #pragma unroll
        for (int m = 1; m < 64; m <<= 1) a += __shfl_xor(a, m);
        acc[jc] = a;
    }
    if (lane < 7) {
        float r = lane == 0 ? acc[0] : lane == 1 ? acc[1] : lane == 2 ? acc[2] :
                  lane == 3 ? acc[3] : lane == 4 ? acc[4] : lane == 5 ? acc[5] : acc[6];
        r += b2f(((const short*)b2)[lane]);
        const size_t oi = (size_t)row * 7 + lane;
        if (fl) ((float*)out)[oi] = r;
        else    ((bf16*)out)[oi] = __float2bfloat16(r);
    }
}

extern "C" void kernel_launch(void* const* d_in, const int* in_sizes, int n_in,
                              void* d_out, int out_size, void* d_ws, size_t ws_size,
                              hipStream_t stream)
{
    const void* xin   = d_in[0];
    const void* eattr = d_in[1];
    const void* Wq    = d_in[2];
    const void* Wk    = d_in[3];
    const void* Wv    = d_in[4];
    const void* WeK   = d_in[5];
    const void* WeV   = d_in[6];
    const void* Wo    = d_in[7];
    const void* ln1s  = d_in[8];
    const void* ln1b  = d_in[9];
    const void* fw1   = d_in[10];
    const void* fb1   = d_in[11];
    const void* fw2   = d_in[12];
    const void* fb2   = d_in[13];
    const void* ln2s  = d_in[14];
    const void* ln2b  = d_in[15];
    const void* hw1   = d_in[16];
    const void* hb1   = d_in[17];
    const void* hw2   = d_in[18];
    const void* hb2   = d_in[19];
    const int*  eidx  = (const int*)d_in[20];
    const int*  srcI  = eidx;
    const int*  dstI  = eidx + NE;

    // ---- workspace carve-up (256B aligned), heavy aliasing ----
    char* base = (char*)d_ws;
    size_t off = 0;
    auto carve = [&](size_t bytes) -> char* {
        char* p = base + off;
        off += (bytes + 255) & ~(size_t)255;
        return p;
    };
    bf16*  x_b    = (bf16*) carve((size_t)NN * HIDN * 2);    // 32 MB, persistent
    bf16*  q_b    = (bf16*) carve((size_t)NN * HIDN * 2);    // 32 MB
    bf16*  k_b    = (bf16*) carve((size_t)NN * HIDN * 2);    // 32 MB
    bf16*  v_b    = (bf16*) carve((size_t)NN * HIDN * 2);    // 32 MB
    bf16*  echunk = (bf16*) carve((size_t)ECH * HIDN * 2);   // 16 MB
    float* p_buf  = (float*)carve((size_t)NE * NHEAD * 4);   //  8 MB
    float* denom  = (float*)carve((size_t)NN * NHEAD * 4);   //  2 MB
    unsigned* flag= (unsigned*)carve(256);
    bf16*  WqT    = (bf16*) carve((size_t)HIDN * HIDN * 2);
    bf16*  WkT    = (bf16*) carve((size_t)HIDN * HIDN * 2);
    bf16*  WvT    = (bf16*) carve((size_t)HIDN * HIDN * 2);
    bf16*  WoT    = (bf16*) carve((size_t)HIDN * HIDN * 2);
    bf16*  WeKT   = (bf16*) carve((size_t)HIDN * EDIM * 2);
    bf16*  WeVT   = (bf16*) carve((size_t)HIDN * EDIM * 2);
    bf16*  W1T    = (bf16*) carve((size_t)FFN * HIDN * 2);
    bf16*  W2T    = (bf16*) carve((size_t)HIDN * FFN * 2);
    bf16*  HW1T   = (bf16*) carve((size_t)HIDN * HIDN * 2);
    bf16*  HW2T   = (bf16*) carve((size_t)8 * HIDN * 2);
    // canonical small vectors
    bf16*  c_ln1s = (bf16*) carve((size_t)2 * HIDN * 2);
    bf16*  c_ln1b = (bf16*) carve((size_t)2 * HIDN * 2);
    bf16*  c_ln2s = (bf16*) carve((size_t)2 * HIDN * 2);
    bf16*  c_ln2b = (bf16*) carve((size_t)2 * HIDN * 2);
    bf16*  c_fb1  = (bf16*) carve((size_t)2 * FFN * 2);
    bf16*  c_fb2  = (bf16*) carve((size_t)2 * HIDN * 2);
    bf16*  c_hb1  = (bf16*) carve((size_t)HIDN * 2);
    bf16*  c_hb2  = (bf16*) carve((size_t)16 * 2);
    if (off > ws_size) return;   // ~156 MB required

    // Aliases over dead regions (phase-ordered):
    float* agg    = (float*)q_b;     // 64 MB = q_b+k_b; live after score pass
    bf16*  tmp_b  = v_b;             // 32 MB; live after agg phase (v dead)
    bf16*  hid    = q_b;             // 64 MB = q_b+k_b; FFN hid chunk (agg dead)
    bf16*  ffnout = v_b;             // 16 MB used (tmp dead after ln1)

    const int TB = 256;
    #define GRID1(n) dim3(((n) + TB - 1) / TB)

    detect_kernel<<<1, 64, 0, stream>>>(xin, flag);

    convert_kernel<<<GRID1(NN * HIDN), TB, 0, stream>>>(xin, 0, x_b, NN * HIDN, flag);
    convert_kernel<<<GRID1(2 * HIDN), TB, 0, stream>>>(ln1s, 0, c_ln1s, 2 * HIDN, flag);
    convert_kernel<<<GRID1(2 * HIDN), TB, 0, stream>>>(ln1b, 0, c_ln1b, 2 * HIDN, flag);
    convert_kernel<<<GRID1(2 * HIDN), TB, 0, stream>>>(ln2s, 0, c_ln2s, 2 * HIDN, flag);
    convert_kernel<<<GRID1(2 * HIDN), TB, 0, stream>>>(ln2b, 0, c_ln2b, 2 * HIDN, flag);
    convert_kernel<<<GRID1(2 * FFN), TB, 0, stream>>>(fb1, 0, c_fb1, 2 * FFN, flag);
    convert_kernel<<<GRID1(2 * HIDN), TB, 0, stream>>>(fb2, 0, c_fb2, 2 * HIDN, flag);
    convert_kernel<<<GRID1(HIDN), TB, 0, stream>>>(hb1, 0, c_hb1, HIDN, flag);
    convert_kernel<<<1, TB, 0, stream>>>(hb2, 0, c_hb2, 7, flag);

    transpose_kernel<<<GRID1(HIDN * HIDN), TB, 0, stream>>>(hw1, 0, HW1T, HIDN, HIDN, flag);
    transpose_kernel<<<GRID1(HIDN * 7), TB, 0, stream>>>(hw2, 0, HW2T, HIDN, 7, flag);

    for (int l = 0; l < 2; ++l) {
        const size_t oW  = (size_t)l * HIDN * HIDN;
        const size_t oWe = (size_t)l * EDIM * HIDN;
        const size_t oF1 = (size_t)l * HIDN * FFN;
        const size_t oF2 = (size_t)l * FFN * HIDN;

        transpose_kernel<<<GRID1(HIDN * HIDN), TB, 0, stream>>>(Wq, oW,  WqT,  HIDN, HIDN, flag);
        transpose_kernel<<<GRID1(HIDN * HIDN), TB, 0, stream>>>(Wk, oW,  WkT,  HIDN, HIDN, flag);
        transpose_kernel<<<GRID1(HIDN * HIDN), TB, 0, stream>>>(Wv, oW,  WvT,  HIDN, HIDN, flag);
        transpose_kernel<<<GRID1(EDIM * HIDN), TB, 0, stream>>>(WeK, oWe, WeKT, EDIM, HIDN, flag);
        transpose_kernel<<<GRID1(EDIM * HIDN), TB, 0, stream>>>(WeV, oWe, WeVT, EDIM, HIDN, flag);
        transpose_kernel<<<GRID1(HIDN * HIDN), TB, 0, stream>>>(Wo, oW,  WoT,  HIDN, HIDN, flag);
        transpose_kernel<<<GRID1(HIDN * FFN),  TB, 0, stream>>>(fw1, oF1, W1T,  HIDN, FFN, flag);
        transpose_kernel<<<GRID1(FFN * HIDN),  TB, 0, stream>>>(fw2, oF2, W2T,  FFN, HIDN, flag);

        // q/k/v projections (canonical bf16 A)
        gemm_kernel<0, false><<<dim3(HIDN/64, NN/64), TB, 0, stream>>>(x_b, 0, WqT, nullptr, q_b, NN, HIDN, HIDN, flag);
        gemm_kernel<0, false><<<dim3(HIDN/64, NN/64), TB, 0, stream>>>(x_b, 0, WkT, nullptr, k_b, NN, HIDN, HIDN, flag);
        gemm_kernel<0, false><<<dim3(HIDN/64, NN/64), TB, 0, stream>>>(x_b, 0, WvT, nullptr, v_b, NN, HIDN, HIDN, flag);

        hipMemsetAsync(denom, 0, (size_t)NN * NHEAD * 4, stream);

        // score pass: eK per chunk (raw-input A, flag mode), then pe + denom
        for (int c = 0; c < NE / ECH; ++c) {
            gemm_kernel<2, false><<<dim3(HIDN/64, ECH/64), TB, 0, stream>>>(
                eattr, (size_t)c * ECH * EDIM, WeKT, nullptr, echunk, ECH, HIDN, EDIM, flag);
            score_kernel<<<ECH / 4, TB, 0, stream>>>(q_b, k_b, echunk, srcI, dstI, p_buf, denom, c * ECH);
        }

        // aggregation pass: q/k dead -> agg overlays them
        hipMemsetAsync(agg, 0, (size_t)NN * HIDN * 4, stream);
        for (int c = 0; c < NE / ECH; ++c) {
            gemm_kernel<2, false><<<dim3(HIDN/64, ECH/64), TB, 0, stream>>>(
                eattr, (size_t)c * ECH * EDIM, WeVT, nullptr, echunk, ECH, HIDN, EDIM, flag);
            agg_kernel<<<ECH / 4, TB, 0, stream>>>(p_buf, denom, v_b, echunk, srcI, dstI, agg, c * ECH);
        }

        // out-proj (fp32 A) -> tmp (overlays v, dead now); then ln1
        gemm_kernel<1, false><<<dim3(HIDN/64, NN/64), TB, 0, stream>>>(agg, 0, WoT, nullptr, tmp_b, NN, HIDN, HIDN, flag);
        ln_kernel<<<NN / 4, TB, 0, stream>>>(x_b, tmp_b, c_ln1s + (size_t)l * HIDN, c_ln1b + (size_t)l * HIDN, 0);

        // FFN in row chunks (hid overlays agg; ffnout overlays tmp)
        for (int r0 = 0; r0 < NN; r0 += RCH) {
            gemm_kernel<0, true ><<<dim3(FFN/64, RCH/64), TB, 0, stream>>>(
                x_b + (size_t)r0 * HIDN, 0, W1T, c_fb1 + (size_t)l * FFN, hid, RCH, FFN, HIDN, flag);
            gemm_kernel<0, false><<<dim3(HIDN/64, RCH/64), TB, 0, stream>>>(
                hid, 0, W2T, c_fb2 + (size_t)l * HIDN, ffnout, RCH, HIDN, FFN, flag);
            ln_kernel<<<RCH / 4, TB, 0, stream>>>(x_b, ffnout, c_ln2s + (size_t)l * HIDN, c_ln2b + (size_t)l * HIDN, r0);
        }
    }

    // head: gelu(x[ASTART:] @ hw1 + hb1) @ hw2 + hb2  (hid overlays q area)
    gemm_kernel<0, true><<<dim3(HIDN/64, NACT/64), TB, 0, stream>>>(
        x_b + (size_t)ASTART * HIDN, 0, HW1T, c_hb1, hid, NACT, HIDN, HIDN, flag);
    head2_kernel<<<NACT / 4, TB, 0, stream>>>(hid, HW2T, c_hb2, d_out, flag);
}

// Round 6
// 3310.316 us; speedup vs baseline: 1.5268x; 1.5268x over previous
//
#include <hip/hip_runtime.h>
#include <hip/hip_bf16.h>
#include <math.h>

// Problem constants (fixed by setup_inputs). All inputs/output are fp32
// (established round 5: runtime dtype-branch fl=1 passed). Internal: bf16.
#define NN     65536
#define NE     262144
#define HIDN   256
#define EDIM   64
#define NHEAD  8
#define HDIM   32
#define FFN    1024
#define ASTART 8192
#define NACT   (NN - ASTART)   // 57344 = 448*128
#define ECH    32768           // edge chunk (8 chunks)
#define RCH    32768           // FFN row chunk (2 chunks)

typedef __attribute__((ext_vector_type(8))) short short8;
typedef __attribute__((ext_vector_type(4))) short short4v;
typedef __attribute__((ext_vector_type(4))) float float4v;
typedef __hip_bfloat16 bf16;

__device__ __forceinline__ float b2f(short s) {
    union { unsigned u; float f; } c;
    c.u = ((unsigned)(unsigned short)s) << 16;
    return c.f;
}
__device__ __forceinline__ short f2b(float f) {
    __hip_bfloat16 h = __float2bfloat16(f);
    return *reinterpret_cast<short*>(&h);
}
__device__ __forceinline__ float gelu_exact(float v) {
    return 0.5f * v * (1.0f + erff(v * 0.70710678118654752f));
}

// async global->LDS 16B per lane; dest = l + lane*16 (wave-uniform l).
__device__ __forceinline__ void gload16(const void* g, void* l) {
    __builtin_amdgcn_global_load_lds(
        (const __attribute__((address_space(1))) void*)(uintptr_t)g,
        (__attribute__((address_space(3))) void*)(unsigned)(uintptr_t)l,
        16, 0, 0);
}

__global__ void convert_kernel(const float* __restrict__ src,
                               bf16* __restrict__ dst, int n) {
    int i = blockIdx.x * 256 + threadIdx.x;
    if (i < n) dst[i] = __float2bfloat16(src[i]);
}

// dst[C x R] = src[R x C]^T  (fp32 in, bf16 out)
__global__ void transpose_kernel(const float* __restrict__ src,
                                 bf16* __restrict__ dst, int R, int Cc) {
    int idx = blockIdx.x * 256 + threadIdx.x;
    if (idx >= R * Cc) return;
    int r = idx / Cc, c = idx - r * Cc;
    dst[(size_t)c * R + r] = __float2bfloat16(src[idx]);
}

// ---------------------------------------------------------------------------
// m97-structure MFMA GEMM: C[M,N] = A[M,K] @ B[K,N] (+bias)(+gelu), C bf16.
// 128x128 block tile, BK=32, 256 thr = 4 waves (2x2), wave tile 64x64
// (4x4 frags of 16x16x32). A/B staged in LDS; B (and bf16 A) via
// global_load_lds width=16; fp32 A (AMODE=1) via register convert+ds_write.
// BT is N x K bf16 (B transposed). M%128==0, N%128==0, K%32==0.
// ---------------------------------------------------------------------------
template<int AMODE, bool DO_GELU>   // AMODE: 0 = bf16 A, 1 = fp32 A
__global__ __launch_bounds__(256) void gemm_kernel(
    const void* __restrict__ A,
    const bf16* __restrict__ BT,
    const bf16* __restrict__ bias,   // length N or nullptr
    bf16* __restrict__ C,
    int M, int Nn, int K)
{
    __shared__ __align__(16) short As[128 * 32];   // 8 KB
    __shared__ __align__(16) short Bs[128 * 32];   // 8 KB

    const int t    = threadIdx.x;
    const int wave = t >> 6;
    const int lane = t & 63;
    const int l15  = lane & 15;
    const int quad = lane >> 4;
    const int wm   = (wave & 1) * 64;
    const int wn   = (wave >> 1) * 64;
    const int bm   = blockIdx.y * 128;
    const int bn   = blockIdx.x * 128;
    const int srow = t >> 2;          // staging row within 64-row chunk
    const int scol = (t & 3) * 8;     // staging col (elements)

    const short* Ab = (const short*)A  + (size_t)(bm + srow) * K + scol;
    const float* Af = (const float*)A  + (size_t)(bm + srow) * K + scol;
    const short* Bb = (const short*)BT + (size_t)(bn + srow) * K + scol;
    char* lA = (char*)As;
    char* lB = (char*)Bs;
    const int offT = t * 16;          // AMODE1 ds_write offset (bytes)
    const int offW = wave * 1024;     // global_load_lds wave base (bytes)

    float4v acc[4][4];
    #pragma unroll
    for (int i = 0; i < 4; ++i)
        #pragma unroll
        for (int j = 0; j < 4; ++j) acc[i][j] = (float4v){0.f, 0.f, 0.f, 0.f};

    for (int k0 = 0; k0 < K; k0 += 32) {
        __syncthreads();
        if (AMODE == 0) {
            gload16(Ab + k0,                lA + offW);
            gload16(Ab + (size_t)64 * K + k0, lA + 4096 + offW);
        } else {
            #pragma unroll
            for (int i = 0; i < 2; ++i) {
                const float* s = Af + (size_t)i * 64 * K + k0;
                float4v f0 = *(const float4v*)s;
                float4v f1 = *(const float4v*)(s + 4);
                short8 w;
                #pragma unroll
                for (int j = 0; j < 4; ++j) { w[j] = f2b(f0[j]); w[4 + j] = f2b(f1[j]); }
                *(short8*)(lA + i * 4096 + offT) = w;
            }
        }
        gload16(Bb + k0,                  lB + offW);
        gload16(Bb + (size_t)64 * K + k0, lB + 4096 + offW);
        __syncthreads();

        short8 afr[4], bfr[4];
        #pragma unroll
        for (int i = 0; i < 4; ++i)
            afr[i] = *(const short8*)(lA + (wm + i * 16 + l15) * 64 + quad * 16);
        #pragma unroll
        for (int j = 0; j < 4; ++j)
            bfr[j] = *(const short8*)(lB + (wn + j * 16 + l15) * 64 + quad * 16);
        #pragma unroll
        for (int i = 0; i < 4; ++i)
            #pragma unroll
            for (int j = 0; j < 4; ++j)
                acc[i][j] = __builtin_amdgcn_mfma_f32_16x16x32_bf16(afr[i], bfr[j], acc[i][j], 0, 0, 0);
    }

    #pragma unroll
    for (int j = 0; j < 4; ++j) {
        const int col = bn + wn + j * 16 + l15;
        const float bv = bias ? b2f(((const short*)bias)[col]) : 0.0f;
        #pragma unroll
        for (int i = 0; i < 4; ++i) {
            const int row0 = bm + wm + i * 16 + quad * 4;
            #pragma unroll
            for (int r = 0; r < 4; ++r) {
                float v = acc[i][j][r] + bv;
                if (DO_GELU) v = gelu_exact(v);
                C[(size_t)(row0 + r) * Nn + col] = __float2bfloat16(v);
            }
        }
    }
}

// One wave per edge: pe = exp(clamp(score)) (shift-free softmax; scores O(1)).
// lane covers channels [lane*4, lane*4+4); head = lane>>3.
__global__ __launch_bounds__(256) void score_kernel(
    const bf16* __restrict__ q, const bf16* __restrict__ k,
    const bf16* __restrict__ eK,              // chunk-local, ECH x 256
    const int* __restrict__ srcIdx, const int* __restrict__ dstIdx,
    float* __restrict__ pbuf, float* __restrict__ denom, int e0)
{
    const int el = blockIdx.x * 4 + (threadIdx.x >> 6);
    const int e  = e0 + el;
    const int lane = threadIdx.x & 63;
    const int s = srcIdx[e], d = dstIdx[e];
    const int off = lane * 4;

    const short4v qv = *(const short4v*)((const short*)q  + (size_t)d  * HIDN + off);
    const short4v kv = *(const short4v*)((const short*)k  + (size_t)s  * HIDN + off);
    const short4v ev = *(const short4v*)((const short*)eK + (size_t)el * HIDN + off);
    float p = 0.f;
    #pragma unroll
    for (int j = 0; j < 4; ++j) p += b2f(qv[j]) * (b2f(kv[j]) + b2f(ev[j]));
    p += __shfl_xor(p, 1);
    p += __shfl_xor(p, 2);
    p += __shfl_xor(p, 4);
    if ((lane & 7) == 0) {
        const int h = lane >> 3;
        const float sc = fminf(fmaxf(p * 0.17677669529663689f, -30.f), 30.f);
        const float pe = expf(sc);
        pbuf[(size_t)e * NHEAD + h] = pe;
        atomicAdd(&denom[(size_t)d * NHEAD + h], pe);
    }
}

// One wave per edge: agg[dst, c] += alpha[h(c)] * (v[src, c] + eV[e, c])
__global__ __launch_bounds__(256) void agg_kernel(
    const float* __restrict__ p, const float* __restrict__ denom,
    const bf16* __restrict__ v, const bf16* __restrict__ eV,   // eV chunk-local
    const int* __restrict__ srcIdx, const int* __restrict__ dstIdx,
    float* __restrict__ agg, int e0)
{
    const int el = blockIdx.x * 4 + (threadIdx.x >> 6);
    const int e  = e0 + el;
    const int lane = threadIdx.x & 63;
    const int s = srcIdx[e], d = dstIdx[e];
    const int h = lane >> 3;
    const float alpha = p[(size_t)e * NHEAD + h] /
                        fmaxf(denom[(size_t)d * NHEAD + h], 1e-37f);
    const int off = lane * 4;
    const short4v vv = *(const short4v*)((const short*)v  + (size_t)s  * HIDN + off);
    const short4v ev = *(const short4v*)((const short*)eV + (size_t)el * HIDN + off);
    float* ao = agg + (size_t)d * HIDN + off;
    #pragma unroll
    for (int j = 0; j < 4; ++j) atomicAdd(ao + j, alpha * (b2f(vv[j]) + b2f(ev[j])));
}

// One wave per row r in [r0, ...): x = LN(x + t)*s + b (in place, bf16).
__global__ __launch_bounds__(256) void ln_kernel(
    bf16* __restrict__ x, const bf16* __restrict__ t,
    const bf16* __restrict__ sc, const bf16* __restrict__ bi, int r0)
{
    const int row = r0 + blockIdx.x * 4 + (threadIdx.x >> 6);
    const int lane = threadIdx.x & 63;
    const size_t base = (size_t)row * HIDN + lane * 4;
    const size_t tbase = (size_t)(row - r0) * HIDN + lane * 4;
    const short4v xv = *(const short4v*)((const short*)x + base);
    const short4v tv = *(const short4v*)((const short*)t + tbase);
    float v[4];
    #pragma unroll
    for (int j = 0; j < 4; ++j) v[j] = b2f(xv[j]) + b2f(tv[j]);
    float sum = v[0] + v[1] + v[2] + v[3];
    float ssq = v[0]*v[0] + v[1]*v[1] + v[2]*v[2] + v[3]*v[3];
    #pragma unroll
    for (int m = 1; m < 64; m <<= 1) { sum += __shfl_xor(sum, m); ssq += __shfl_xor(ssq, m); }
    const float mean = sum * (1.0f / 256.0f);
    const float var  = fmaxf(ssq * (1.0f / 256.0f) - mean * mean, 0.0f);
    const float rstd = rsqrtf(var + 1e-5f);
    const short4v sv = *(const short4v*)((const short*)sc + lane * 4);
    const short4v bv = *(const short4v*)((const short*)bi + lane * 4);
    short4v out;
    #pragma unroll
    for (int j = 0; j < 4; ++j)
        out[j] = f2b((v[j] - mean) * rstd * b2f(sv[j]) + b2f(bv[j]));
    *(short4v*)((short*)x + base) = out;
}

// One wave per row: out[row, 0..6] = h1[row,:] @ w2 + b2  (fp32 out).
__global__ __launch_bounds__(256) void head2_kernel(
    const bf16* __restrict__ h1, const bf16* __restrict__ w2T,
    const bf16* __restrict__ b2, float* __restrict__ out)
{
    const int row = blockIdx.x * 4 + (threadIdx.x >> 6);
    const int lane = threadIdx.x & 63;
    const int off = lane * 4;
    const short4v hv = *(const short4v*)((const short*)h1 + (size_t)row * HIDN + off);
    float hf[4];
    #pragma unroll
    for (int j = 0; j < 4; ++j) hf[j] = b2f(hv[j]);
    float acc[7];
    #pragma unroll
    for (int jc = 0; jc < 7; ++jc) {
        const short4v wv = *(const short4v*)((const short*)w2T + jc * HIDN + off);
        float a = hf[0]*b2f(wv[0]) + hf[1]*b2f(wv[1]) + hf[2]*b2f(wv[2]) + hf[3]*b2f(wv[3]);
        #pragma unroll
        for (int m = 1; m < 64; m <<= 1) a += __shfl_xor(a, m);
        acc[jc] = a;
    }
    if (lane < 7) {
        float r = lane == 0 ? acc[0] : lane == 1 ? acc[1] : lane == 2 ? acc[2] :
                  lane == 3 ? acc[3] : lane == 4 ? acc[4] : lane == 5 ? acc[5] : acc[6];
        out[(size_t)row * 7 + lane] = r + b2f(((const short*)b2)[lane]);
    }
}

extern "C" void kernel_launch(void* const* d_in, const int* in_sizes, int n_in,
                              void* d_out, int out_size, void* d_ws, size_t ws_size,
                              hipStream_t stream)
{
    const float* xin   = (const float*)d_in[0];
    const float* eattr = (const float*)d_in[1];
    const float* Wq    = (const float*)d_in[2];
    const float* Wk    = (const float*)d_in[3];
    const float* Wv    = (const float*)d_in[4];
    const float* WeK   = (const float*)d_in[5];
    const float* WeV   = (const float*)d_in[6];
    const float* Wo    = (const float*)d_in[7];
    const float* ln1s  = (const float*)d_in[8];
    const float* ln1b  = (const float*)d_in[9];
    const float* fw1   = (const float*)d_in[10];
    const float* fb1   = (const float*)d_in[11];
    const float* fw2   = (const float*)d_in[12];
    const float* fb2   = (const float*)d_in[13];
    const float* ln2s  = (const float*)d_in[14];
    const float* ln2b  = (const float*)d_in[15];
    const float* hw1   = (const float*)d_in[16];
    const float* hb1   = (const float*)d_in[17];
    const float* hw2   = (const float*)d_in[18];
    const float* hb2   = (const float*)d_in[19];
    const int*  eidx   = (const int*)d_in[20];
    const int*  srcI   = eidx;
    const int*  dstI   = eidx + NE;

    // ---- workspace carve-up (256B aligned), heavy aliasing (~156 MB) ----
    char* base = (char*)d_ws;
    size_t off = 0;
    auto carve = [&](size_t bytes) -> char* {
        char* p = base + off;
        off += (bytes + 255) & ~(size_t)255;
        return p;
    };
    bf16*  x_b    = (bf16*) carve((size_t)NN * HIDN * 2);    // 32 MB, persistent
    bf16*  q_b    = (bf16*) carve((size_t)NN * HIDN * 2);    // 32 MB
    bf16*  k_b    = (bf16*) carve((size_t)NN * HIDN * 2);    // 32 MB
    bf16*  v_b    = (bf16*) carve((size_t)NN * HIDN * 2);    // 32 MB
    bf16*  echunk = (bf16*) carve((size_t)ECH * HIDN * 2);   // 16 MB
    float* p_buf  = (float*)carve((size_t)NE * NHEAD * 4);   //  8 MB
    float* denom  = (float*)carve((size_t)NN * NHEAD * 4);   //  2 MB
    bf16*  WqT    = (bf16*) carve((size_t)HIDN * HIDN * 2);
    bf16*  WkT    = (bf16*) carve((size_t)HIDN * HIDN * 2);
    bf16*  WvT    = (bf16*) carve((size_t)HIDN * HIDN * 2);
    bf16*  WoT    = (bf16*) carve((size_t)HIDN * HIDN * 2);
    bf16*  WeKT   = (bf16*) carve((size_t)HIDN * EDIM * 2);
    bf16*  WeVT   = (bf16*) carve((size_t)HIDN * EDIM * 2);
    bf16*  W1T    = (bf16*) carve((size_t)FFN * HIDN * 2);
    bf16*  W2T    = (bf16*) carve((size_t)HIDN * FFN * 2);
    bf16*  HW1T   = (bf16*) carve((size_t)HIDN * HIDN * 2);
    bf16*  HW2T   = (bf16*) carve((size_t)8 * HIDN * 2);
    bf16*  c_ln1s = (bf16*) carve((size_t)2 * HIDN * 2);
    bf16*  c_ln1b = (bf16*) carve((size_t)2 * HIDN * 2);
    bf16*  c_ln2s = (bf16*) carve((size_t)2 * HIDN * 2);
    bf16*  c_ln2b = (bf16*) carve((size_t)2 * HIDN * 2);
    bf16*  c_fb1  = (bf16*) carve((size_t)2 * FFN * 2);
    bf16*  c_fb2  = (bf16*) carve((size_t)2 * HIDN * 2);
    bf16*  c_hb1  = (bf16*) carve((size_t)HIDN * 2);
    bf16*  c_hb2  = (bf16*) carve((size_t)16 * 2);
    if (off > ws_size) return;

    // Aliases over dead regions (phase-ordered):
    float* agg    = (float*)q_b;     // 64 MB = q_b+k_b; live after score pass
    bf16*  tmp_b  = v_b;             // 32 MB; live after agg phase (v dead)
    bf16*  hid    = q_b;             // 64 MB = q_b+k_b; FFN hid chunk (agg dead)
    bf16*  ffnout = v_b;             // 16 MB used (tmp dead after ln1)

    const int TB = 256;
    #define GRID1(n) dim3(((n) + TB - 1) / TB)

    convert_kernel<<<GRID1(NN * HIDN), TB, 0, stream>>>(xin, x_b, NN * HIDN);
    convert_kernel<<<GRID1(2 * HIDN), TB, 0, stream>>>(ln1s, c_ln1s, 2 * HIDN);
    convert_kernel<<<GRID1(2 * HIDN), TB, 0, stream>>>(ln1b, c_ln1b, 2 * HIDN);
    convert_kernel<<<GRID1(2 * HIDN), TB, 0, stream>>>(ln2s, c_ln2s, 2 * HIDN);
    convert_kernel<<<GRID1(2 * HIDN), TB, 0, stream>>>(ln2b, c_ln2b, 2 * HIDN);
    convert_kernel<<<GRID1(2 * FFN), TB, 0, stream>>>(fb1, c_fb1, 2 * FFN);
    convert_kernel<<<GRID1(2 * HIDN), TB, 0, stream>>>(fb2, c_fb2, 2 * HIDN);
    convert_kernel<<<GRID1(HIDN), TB, 0, stream>>>(hb1, c_hb1, HIDN);
    convert_kernel<<<1, TB, 0, stream>>>(hb2, c_hb2, 7);

    transpose_kernel<<<GRID1(HIDN * HIDN), TB, 0, stream>>>(hw1, HW1T, HIDN, HIDN);
    transpose_kernel<<<GRID1(HIDN * 7), TB, 0, stream>>>(hw2, HW2T, HIDN, 7);

    for (int l = 0; l < 2; ++l) {
        transpose_kernel<<<GRID1(HIDN * HIDN), TB, 0, stream>>>(Wq + (size_t)l*HIDN*HIDN, WqT, HIDN, HIDN);
        transpose_kernel<<<GRID1(HIDN * HIDN), TB, 0, stream>>>(Wk + (size_t)l*HIDN*HIDN, WkT, HIDN, HIDN);
        transpose_kernel<<<GRID1(HIDN * HIDN), TB, 0, stream>>>(Wv + (size_t)l*HIDN*HIDN, WvT, HIDN, HIDN);
        transpose_kernel<<<GRID1(EDIM * HIDN), TB, 0, stream>>>(WeK + (size_t)l*EDIM*HIDN, WeKT, EDIM, HIDN);
        transpose_kernel<<<GRID1(EDIM * HIDN), TB, 0, stream>>>(WeV + (size_t)l*EDIM*HIDN, WeVT, EDIM, HIDN);
        transpose_kernel<<<GRID1(HIDN * HIDN), TB, 0, stream>>>(Wo + (size_t)l*HIDN*HIDN, WoT, HIDN, HIDN);
        transpose_kernel<<<GRID1(HIDN * FFN),  TB, 0, stream>>>(fw1 + (size_t)l*HIDN*FFN, W1T, HIDN, FFN);
        transpose_kernel<<<GRID1(FFN * HIDN),  TB, 0, stream>>>(fw2 + (size_t)l*FFN*HIDN, W2T, FFN, HIDN);

        // q/k/v projections (bf16 A path)
        gemm_kernel<0, false><<<dim3(HIDN/128, NN/128), TB, 0, stream>>>(x_b, WqT, nullptr, q_b, NN, HIDN, HIDN);
        gemm_kernel<0, false><<<dim3(HIDN/128, NN/128), TB, 0, stream>>>(x_b, WkT, nullptr, k_b, NN, HIDN, HIDN);
        gemm_kernel<0, false><<<dim3(HIDN/128, NN/128), TB, 0, stream>>>(x_b, WvT, nullptr, v_b, NN, HIDN, HIDN);

        hipMemsetAsync(denom, 0, (size_t)NN * NHEAD * 4, stream);

        // score pass: eK per chunk (fp32 A path from raw eattr), then pe+denom
        for (int c = 0; c < NE / ECH; ++c) {
            gemm_kernel<1, false><<<dim3(HIDN/128, ECH/128), TB, 0, stream>>>(
                eattr + (size_t)c * ECH * EDIM, WeKT, nullptr, echunk, ECH, HIDN, EDIM);
            score_kernel<<<ECH / 4, TB, 0, stream>>>(q_b, k_b, echunk, srcI, dstI, p_buf, denom, c * ECH);
        }

        // aggregation pass: q/k dead -> agg overlays them
        hipMemsetAsync(agg, 0, (size_t)NN * HIDN * 4, stream);
        for (int c = 0; c < NE / ECH; ++c) {
            gemm_kernel<1, false><<<dim3(HIDN/128, ECH/128), TB, 0, stream>>>(
                eattr + (size_t)c * ECH * EDIM, WeVT, nullptr, echunk, ECH, HIDN, EDIM);
            agg_kernel<<<ECH / 4, TB, 0, stream>>>(p_buf, denom, v_b, echunk, srcI, dstI, agg, c * ECH);
        }

        // out-proj (fp32 A = agg) -> tmp (overlays v, dead now); then ln1
        gemm_kernel<1, false><<<dim3(HIDN/128, NN/128), TB, 0, stream>>>(agg, WoT, nullptr, tmp_b, NN, HIDN, HIDN);
        ln_kernel<<<NN / 4, TB, 0, stream>>>(x_b, tmp_b, c_ln1s + (size_t)l * HIDN, c_ln1b + (size_t)l * HIDN, 0);

        // FFN in row chunks (hid overlays agg; ffnout overlays tmp)
        for (int r0 = 0; r0 < NN; r0 += RCH) {
            gemm_kernel<0, true ><<<dim3(FFN/128, RCH/128), TB, 0, stream>>>(
                x_b + (size_t)r0 * HIDN, W1T, c_fb1 + (size_t)l * FFN, hid, RCH, FFN, HIDN);
            gemm_kernel<0, false><<<dim3(HIDN/128, RCH/128), TB, 0, stream>>>(
                hid, W2T, c_fb2 + (size_t)l * HIDN, ffnout, RCH, HIDN, FFN);
            ln_kernel<<<RCH / 4, TB, 0, stream>>>(x_b, ffnout, c_ln2s + (size_t)l * HIDN, c_ln2b + (size_t)l * HIDN, r0);
        }
    }

    // head: gelu(x[ASTART:] @ hw1 + hb1) @ hw2 + hb2  (hid overlays q area)
    gemm_kernel<0, true><<<dim3(HIDN/128, NACT/128), TB, 0, stream>>>(
        x_b + (size_t)ASTART * HIDN, HW1T, c_hb1, hid, NACT, HIDN, HIDN);
    head2_kernel<<<NACT / 4, TB, 0, stream>>>(hid, HW2T, c_hb2, (float*)d_out);
}

// Round 7
// 1725.937 us; speedup vs baseline: 2.9283x; 1.9180x over previous
//
#include <hip/hip_runtime.h>
#include <hip/hip_bf16.h>
#include <math.h>

// Problem constants (fixed by setup_inputs). All inputs/output are fp32
// (established round 5). Internal compute: bf16 MFMA + fp32 accumulation.
#define NN     65536
#define NE     262144
#define HIDN   256
#define EDIM   64
#define NHEAD  8
#define FFN    1024
#define ASTART 8192
#define NACT   (NN - ASTART)   // 57344 = 448*128
#define NCH    32768           // edges per chunk (8 chunks)
#define NCHUNK (NE / NCH)
#define DPC    (NN / NCHUNK)   // expected dsts per chunk = 8192
#define RCH    32768           // FFN row chunk

typedef __attribute__((ext_vector_type(8))) short short8;
typedef __attribute__((ext_vector_type(4))) short short4v;
typedef __attribute__((ext_vector_type(4))) float float4v;
typedef __hip_bfloat16 bf16;

__device__ __forceinline__ float b2f(short s) {
    union { unsigned u; float f; } c;
    c.u = ((unsigned)(unsigned short)s) << 16;
    return c.f;
}
__device__ __forceinline__ short f2b(float f) {
    __hip_bfloat16 h = __float2bfloat16(f);
    return *reinterpret_cast<short*>(&h);
}
__device__ __forceinline__ float gelu_exact(float v) {
    return 0.5f * v * (1.0f + erff(v * 0.70710678118654752f));
}
// async global->LDS 16B per lane; LDS dest = base + lane*16 (wave-uniform base).
__device__ __forceinline__ void gload16(const void* g, void* l) {
    __builtin_amdgcn_global_load_lds(
        (const __attribute__((address_space(1))) void*)(uintptr_t)g,
        (__attribute__((address_space(3))) void*)(unsigned)(uintptr_t)l,
        16, 0, 0);
}

__global__ void convert_kernel(const float* __restrict__ src,
                               bf16* __restrict__ dst, int n) {
    int i = blockIdx.x * 256 + threadIdx.x;
    if (i < n) dst[i] = __float2bfloat16(src[i]);
}

// dst[C x R] = src[R x C]^T  (fp32 in, bf16 out)
__global__ void transpose_kernel(const float* __restrict__ src,
                                 bf16* __restrict__ dst, int R, int Cc) {
    int idx = blockIdx.x * 256 + threadIdx.x;
    if (idx >= R * Cc) return;
    int r = idx / Cc, c = idx - r * Cc;
    dst[(size_t)c * R + r] = __float2bfloat16(src[idx]);
}

// ---------------- CSR build (edge_index is constant across layers) ----------
__global__ void hist_kernel(const int* __restrict__ dstI, int* __restrict__ cnt) {
    int i = blockIdx.x * 256 + threadIdx.x;
    if (i < NE) atomicAdd(&cnt[dstI[i]], 1);
}
__global__ void scan1_kernel(const int* __restrict__ cnt, int* __restrict__ rp,
                             int* __restrict__ bsum) {
    __shared__ int s[256];
    int t = threadIdx.x, i = blockIdx.x * 256 + t;
    int v = cnt[i]; s[t] = v; __syncthreads();
    for (int off = 1; off < 256; off <<= 1) {
        int x = (t >= off) ? s[t - off] : 0; __syncthreads();
        s[t] += x; __syncthreads();
    }
    rp[i] = s[t] - v;
    if (t == 255) bsum[blockIdx.x] = s[255];
}
__global__ void scan2_kernel(int* __restrict__ bsum) {
    __shared__ int s[256];
    int t = threadIdx.x; int v = bsum[t]; s[t] = v; __syncthreads();
    for (int off = 1; off < 256; off <<= 1) {
        int x = (t >= off) ? s[t - off] : 0; __syncthreads();
        s[t] += x; __syncthreads();
    }
    bsum[t] = s[t] - v;
}
__global__ void scan3_kernel(int* __restrict__ rp, const int* __restrict__ bsum,
                             int* __restrict__ cursor) {
    int i = blockIdx.x * 256 + threadIdx.x;
    int v = rp[i] + bsum[i >> 8];
    rp[i] = v; cursor[i] = v;
    if (i == 0) rp[NN] = NE;
}
__global__ void scatter_kernel(const int* __restrict__ srcI, const int* __restrict__ dstI,
                               int* __restrict__ cursor, int* __restrict__ perm,
                               int* __restrict__ src_s, int* __restrict__ dst_s) {
    int e = blockIdx.x * 256 + threadIdx.x;
    if (e >= NE) return;
    int d = dstI[e];
    int pos = atomicAdd(&cursor[d], 1);
    perm[pos] = e; src_s[pos] = srcI[e]; dst_s[pos] = d;
}

// ---------------------------------------------------------------------------
// m97-structure MFMA GEMM: C[M,N] = A[M,K] @ B[K,N] (+bias)(+gelu), C bf16.
// 128x128 tile, BK=32, 4 waves (2x2), wave 64x64 = 4x4 16x16x32 frags.
// AMODE: 0 = bf16 A (global_load_lds); 1 = fp32 A (convert+ds_write);
//        2 = fp32 A with row gather through perm[] (sorted-edge GEMMs).
// BT is N x K bf16. M%128==0, N%128==0, K%32==0.
// ---------------------------------------------------------------------------
template<int AMODE, bool DO_GELU>
__global__ __launch_bounds__(256) void gemm_kernel(
    const void* __restrict__ A,
    const bf16* __restrict__ BT,
    const bf16* __restrict__ bias,
    bf16* __restrict__ C,
    int M, int Nn, int K,
    const int* __restrict__ perm)
{
    __shared__ __align__(16) short As[128 * 32];
    __shared__ __align__(16) short Bs[128 * 32];

    const int t    = threadIdx.x;
    const int wave = t >> 6;
    const int lane = t & 63;
    const int l15  = lane & 15;
    const int quad = lane >> 4;
    const int wm   = (wave & 1) * 64;
    const int wn   = (wave >> 1) * 64;
    const int bm   = blockIdx.y * 128;
    const int bn   = blockIdx.x * 128;
    const int srow = t >> 2;
    const int scol = (t & 3) * 8;

    const short* Ab = (const short*)A  + (size_t)(bm + srow) * K + scol;
    const short* Bb = (const short*)BT + (size_t)(bn + srow) * K + scol;
    const float* Af0;
    const float* Af1;
    if (AMODE == 1) {
        Af0 = (const float*)A + (size_t)(bm + srow) * K + scol;
        Af1 = Af0 + (size_t)64 * K;
    } else if (AMODE == 2) {
        const int pr0 = perm[bm + srow];
        const int pr1 = perm[bm + 64 + srow];
        Af0 = (const float*)A + (size_t)pr0 * K + scol;
        Af1 = (const float*)A + (size_t)pr1 * K + scol;
    }
    char* lA = (char*)As;
    char* lB = (char*)Bs;
    const int offT = t * 16;
    const int offW = wave * 1024;

    float4v acc[4][4];
    #pragma unroll
    for (int i = 0; i < 4; ++i)
        #pragma unroll
        for (int j = 0; j < 4; ++j) acc[i][j] = (float4v){0.f, 0.f, 0.f, 0.f};

    for (int k0 = 0; k0 < K; k0 += 32) {
        __syncthreads();
        if (AMODE == 0) {
            gload16(Ab + k0,                  lA + offW);
            gload16(Ab + (size_t)64 * K + k0, lA + 4096 + offW);
        } else {
            const float* s0 = Af0 + k0;
            const float* s1 = Af1 + k0;
            #pragma unroll
            for (int i = 0; i < 2; ++i) {
                const float* s = i ? s1 : s0;
                float4v f0 = *(const float4v*)s;
                float4v f1 = *(const float4v*)(s + 4);
                short8 w;
                #pragma unroll
                for (int j = 0; j < 4; ++j) { w[j] = f2b(f0[j]); w[4 + j] = f2b(f1[j]); }
                *(short8*)(lA + i * 4096 + offT) = w;
            }
        }
        gload16(Bb + k0,                  lB + offW);
        gload16(Bb + (size_t)64 * K + k0, lB + 4096 + offW);
        __syncthreads();

        short8 afr[4], bfr[4];
        #pragma unroll
        for (int i = 0; i < 4; ++i)
            afr[i] = *(const short8*)(lA + (wm + i * 16 + l15) * 64 + quad * 16);
        #pragma unroll
        for (int j = 0; j < 4; ++j)
            bfr[j] = *(const short8*)(lB + (wn + j * 16 + l15) * 64 + quad * 16);
        #pragma unroll
        for (int i = 0; i < 4; ++i)
            #pragma unroll
            for (int j = 0; j < 4; ++j)
                acc[i][j] = __builtin_amdgcn_mfma_f32_16x16x32_bf16(afr[i], bfr[j], acc[i][j], 0, 0, 0);
    }

    #pragma unroll
    for (int j = 0; j < 4; ++j) {
        const int col = bn + wn + j * 16 + l15;
        const float bv = bias ? b2f(((const short*)bias)[col]) : 0.0f;
        #pragma unroll
        for (int i = 0; i < 4; ++i) {
            const int row0 = bm + wm + i * 16 + quad * 4;
            #pragma unroll
            for (int r = 0; r < 4; ++r) {
                float v = acc[i][j][r] + bv;
                if (DO_GELU) v = gelu_exact(v);
                C[(size_t)(row0 + r) * Nn + col] = __float2bfloat16(v);
            }
        }
    }
}

// One wave per sorted edge pos p: pe = exp(clamp(score)); pbuf[p*8+h] (bf16).
// No atomics. lane covers channels [lane*4, lane*4+4); head = lane>>3.
__global__ __launch_bounds__(256) void score_kernel(
    const bf16* __restrict__ q, const bf16* __restrict__ k,
    const bf16* __restrict__ eK,              // chunk-local, NCH x 256
    const int* __restrict__ src_s, const int* __restrict__ dst_s,
    short* __restrict__ pbuf, int e0)
{
    const int p = e0 + blockIdx.x * 4 + (threadIdx.x >> 6);
    const int lane = threadIdx.x & 63;
    const int s = src_s[p], d = dst_s[p];
    const int off = lane * 4;

    const short4v qv = *(const short4v*)((const short*)q  + (size_t)d * HIDN + off);
    const short4v kv = *(const short4v*)((const short*)k  + (size_t)s * HIDN + off);
    const short4v ev = *(const short4v*)((const short*)eK + (size_t)(p - e0) * HIDN + off);
    float x = 0.f;
    #pragma unroll
    for (int j = 0; j < 4; ++j) x += b2f(qv[j]) * (b2f(kv[j]) + b2f(ev[j]));
    x += __shfl_xor(x, 1);
    x += __shfl_xor(x, 2);
    x += __shfl_xor(x, 4);
    if ((lane & 7) == 0) {
        const float sc = fminf(fmaxf(x * 0.17677669529663689f, -30.f), 30.f);
        pbuf[(size_t)p * NHEAD + (lane >> 3)] = f2b(expf(sc));
    }
}

// One wave per dst d in [dlo, ...): gather-aggregate its edges within chunk
// [e0,e1). den from full pbuf range; interior dst -> plain float4 store;
// chunk-straddling dst -> atomicAdd partials (agg pre-zeroed).
__global__ __launch_bounds__(256) void agg_kernel(
    const short* __restrict__ pbuf, const bf16* __restrict__ v,
    const bf16* __restrict__ eV,              // chunk-local, NCH x 256
    const int* __restrict__ src_s, const int* __restrict__ rp,
    float* __restrict__ agg, int e0, int e1, int dlo)
{
    const int d = dlo + blockIdx.x * 4 + (threadIdx.x >> 6);
    const int lane = threadIdx.x & 63;
    const int es = rp[d], ee = rp[d + 1];
    const int lo = es > e0 ? es : e0;
    const int hi = ee < e1 ? ee : e1;
    if (lo >= hi) return;
    const int h = lane >> 3, off = lane * 4;

    float den = 0.f;
    for (int p = es; p < ee; ++p) den += b2f(pbuf[(size_t)p * NHEAD + h]);

    float a0 = 0.f, a1 = 0.f, a2 = 0.f, a3 = 0.f;
    for (int p = lo; p < hi; ++p) {
        const float al = b2f(pbuf[(size_t)p * NHEAD + h]) / den;
        const int s = src_s[p];
        const short4v vv = *(const short4v*)((const short*)v  + (size_t)s * HIDN + off);
        const short4v ev = *(const short4v*)((const short*)eV + (size_t)(p - e0) * HIDN + off);
        a0 += al * (b2f(vv[0]) + b2f(ev[0]));
        a1 += al * (b2f(vv[1]) + b2f(ev[1]));
        a2 += al * (b2f(vv[2]) + b2f(ev[2]));
        a3 += al * (b2f(vv[3]) + b2f(ev[3]));
    }
    float* ao = agg + (size_t)d * HIDN + off;
    if (es >= e0 && ee <= e1) {
        *(float4v*)ao = (float4v){a0, a1, a2, a3};
    } else {
        atomicAdd(ao + 0, a0); atomicAdd(ao + 1, a1);
        atomicAdd(ao + 2, a2); atomicAdd(ao + 3, a3);
    }
}

// One wave per row r in [r0, ...): x = LN(x + t)*s + b (in place, bf16).
__global__ __launch_bounds__(256) void ln_kernel(
    bf16* __restrict__ x, const bf16* __restrict__ t,
    const bf16* __restrict__ sc, const bf16* __restrict__ bi, int r0)
{
    const int row = r0 + blockIdx.x * 4 + (threadIdx.x >> 6);
    const int lane = threadIdx.x & 63;
    const size_t base = (size_t)row * HIDN + lane * 4;
    const size_t tbase = (size_t)(row - r0) * HIDN + lane * 4;
    const short4v xv = *(const short4v*)((const short*)x + base);
    const short4v tv = *(const short4v*)((const short*)t + tbase);
    float v[4];
    #pragma unroll
    for (int j = 0; j < 4; ++j) v[j] = b2f(xv[j]) + b2f(tv[j]);
    float sum = v[0] + v[1] + v[2] + v[3];
    float ssq = v[0]*v[0] + v[1]*v[1] + v[2]*v[2] + v[3]*v[3];
    #pragma unroll
    for (int m = 1; m < 64; m <<= 1) { sum += __shfl_xor(sum, m); ssq += __shfl_xor(ssq, m); }
    const float mean = sum * (1.0f / 256.0f);
    const float var  = fmaxf(ssq * (1.0f / 256.0f) - mean * mean, 0.0f);
    const float rstd = rsqrtf(var + 1e-5f);
    const short4v sv = *(const short4v*)((const short*)sc + lane * 4);
    const short4v bv = *(const short4v*)((const short*)bi + lane * 4);
    short4v out;
    #pragma unroll
    for (int j = 0; j < 4; ++j)
        out[j] = f2b((v[j] - mean) * rstd * b2f(sv[j]) + b2f(bv[j]));
    *(short4v*)((short*)x + base) = out;
}

// One wave per row: out[row, 0..6] = h1[row,:] @ w2 + b2  (fp32 out).
__global__ __launch_bounds__(256) void head2_kernel(
    const bf16* __restrict__ h1, const bf16* __restrict__ w2T,
    const bf16* __restrict__ b2, float* __restrict__ out)
{
    const int row = blockIdx.x * 4 + (threadIdx.x >> 6);
    const int lane = threadIdx.x & 63;
    const int off = lane * 4;
    const short4v hv = *(const short4v*)((const short*)h1 + (size_t)row * HIDN + off);
    float hf[4];
    #pragma unroll
    for (int j = 0; j < 4; ++j) hf[j] = b2f(hv[j]);
    float acc[7];
    #pragma unroll
    for (int jc = 0; jc < 7; ++jc) {
        const short4v wv = *(const short4v*)((const short*)w2T + jc * HIDN + off);
        float a = hf[0]*b2f(wv[0]) + hf[1]*b2f(wv[1]) + hf[2]*b2f(wv[2]) + hf[3]*b2f(wv[3]);
        #pragma unroll
        for (int m = 1; m < 64; m <<= 1) a += __shfl_xor(a, m);
        acc[jc] = a;
    }
    if (lane < 7) {
        float r = lane == 0 ? acc[0] : lane == 1 ? acc[1] : lane == 2 ? acc[2] :
                  lane == 3 ? acc[3] : lane == 4 ? acc[4] : lane == 5 ? acc[5] : acc[6];
        out[(size_t)row * 7 + lane] = r + b2f(((const short*)b2)[lane]);
    }
}

extern "C" void kernel_launch(void* const* d_in, const int* in_sizes, int n_in,
                              void* d_out, int out_size, void* d_ws, size_t ws_size,
                              hipStream_t stream)
{
    const float* xin   = (const float*)d_in[0];
    const float* eattr = (const float*)d_in[1];
    const float* Wq    = (const float*)d_in[2];
    const float* Wk    = (const float*)d_in[3];
    const float* Wv    = (const float*)d_in[4];
    const float* WeK   = (const float*)d_in[5];
    const float* WeV   = (const float*)d_in[6];
    const float* Wo    = (const float*)d_in[7];
    const float* ln1s  = (const float*)d_in[8];
    const float* ln1b  = (const float*)d_in[9];
    const float* fw1   = (const float*)d_in[10];
    const float* fb1   = (const float*)d_in[11];
    const float* fw2   = (const float*)d_in[12];
    const float* fb2   = (const float*)d_in[13];
    const float* ln2s  = (const float*)d_in[14];
    const float* ln2b  = (const float*)d_in[15];
    const float* hw1   = (const float*)d_in[16];
    const float* hb1   = (const float*)d_in[17];
    const float* hw2   = (const float*)d_in[18];
    const float* hb2   = (const float*)d_in[19];
    const int*  eidx   = (const int*)d_in[20];
    const int*  srcI   = eidx;
    const int*  dstI   = eidx + NE;

    // ---- workspace carve-up (256B aligned), ~153 MB ----
    char* base = (char*)d_ws;
    size_t off = 0;
    auto carve = [&](size_t bytes) -> char* {
        char* p = base + off;
        off += (bytes + 255) & ~(size_t)255;
        return p;
    };
    bf16*  x_b    = (bf16*) carve((size_t)NN * HIDN * 2);    // 32 MB persistent
    bf16*  q_b    = (bf16*) carve((size_t)NN * HIDN * 2);    // 32 MB
    bf16*  k_b    = (bf16*) carve((size_t)NN * HIDN * 2);    // 32 MB
    bf16*  v_b    = (bf16*) carve((size_t)NN * HIDN * 2);    // 32 MB
    bf16*  echunk = (bf16*) carve((size_t)NCH * HIDN * 2);   // 16 MB (also CSR scratch)
    short* pbuf   = (short*)carve((size_t)NE * NHEAD * 2);   //  4 MB (bf16 pe)
    int*   perm   = (int*)  carve((size_t)NE * 4);           //  1 MB
    int*   src_s  = (int*)  carve((size_t)NE * 4);           //  1 MB
    int*   dst_s  = (int*)  carve((size_t)NE * 4);           //  1 MB
    int*   rowp   = (int*)  carve((size_t)(NN + 1) * 4);     // .25 MB
    bf16*  WqT    = (bf16*) carve((size_t)HIDN * HIDN * 2);
    bf16*  WkT    = (bf16*) carve((size_t)HIDN * HIDN * 2);
    bf16*  WvT    = (bf16*) carve((size_t)HIDN * HIDN * 2);
    bf16*  WoT    = (bf16*) carve((size_t)HIDN * HIDN * 2);
    bf16*  WeKT   = (bf16*) carve((size_t)HIDN * EDIM * 2);
    bf16*  WeVT   = (bf16*) carve((size_t)HIDN * EDIM * 2);
    bf16*  W1T    = (bf16*) carve((size_t)FFN * HIDN * 2);
    bf16*  W2T    = (bf16*) carve((size_t)HIDN * FFN * 2);
    bf16*  HW1T   = (bf16*) carve((size_t)HIDN * HIDN * 2);
    bf16*  HW2T   = (bf16*) carve((size_t)8 * HIDN * 2);
    bf16*  c_ln1s = (bf16*) carve((size_t)2 * HIDN * 2);
    bf16*  c_ln1b = (bf16*) carve((size_t)2 * HIDN * 2);
    bf16*  c_ln2s = (bf16*) carve((size_t)2 * HIDN * 2);
    bf16*  c_ln2b = (bf16*) carve((size_t)2 * HIDN * 2);
    bf16*  c_fb1  = (bf16*) carve((size_t)2 * FFN * 2);
    bf16*  c_fb2  = (bf16*) carve((size_t)2 * HIDN * 2);
    bf16*  c_hb1  = (bf16*) carve((size_t)HIDN * 2);
    bf16*  c_hb2  = (bf16*) carve((size_t)16 * 2);
    if (off > ws_size) return;

    // CSR build scratch inside echunk (dead until layer loop):
    int* cnt    = (int*)echunk;            // NN ints
    int* cursor = cnt + NN;                // NN ints
    int* bsum   = cursor + NN;             // 256 ints
    // Phase aliases (as in round 6):
    float* agg    = (float*)q_b;   // 64 MB over q+k (dead during agg phase)
    bf16*  tmp_b  = v_b;           // out-proj output (v dead after agg)
    bf16*  hid    = q_b;           // FFN hidden (agg dead after out-proj)
    bf16*  ffnout = v_b;

    const int TB = 256;
    #define GRID1(n) dim3(((n) + TB - 1) / TB)

    convert_kernel<<<GRID1(NN * HIDN), TB, 0, stream>>>(xin, x_b, NN * HIDN);
    convert_kernel<<<GRID1(2 * HIDN), TB, 0, stream>>>(ln1s, c_ln1s, 2 * HIDN);
    convert_kernel<<<GRID1(2 * HIDN), TB, 0, stream>>>(ln1b, c_ln1b, 2 * HIDN);
    convert_kernel<<<GRID1(2 * HIDN), TB, 0, stream>>>(ln2s, c_ln2s, 2 * HIDN);
    convert_kernel<<<GRID1(2 * HIDN), TB, 0, stream>>>(ln2b, c_ln2b, 2 * HIDN);
    convert_kernel<<<GRID1(2 * FFN), TB, 0, stream>>>(fb1, c_fb1, 2 * FFN);
    convert_kernel<<<GRID1(2 * HIDN), TB, 0, stream>>>(fb2, c_fb2, 2 * HIDN);
    convert_kernel<<<GRID1(HIDN), TB, 0, stream>>>(hb1, c_hb1, HIDN);
    convert_kernel<<<1, TB, 0, stream>>>(hb2, c_hb2, 7);
    transpose_kernel<<<GRID1(HIDN * HIDN), TB, 0, stream>>>(hw1, HW1T, HIDN, HIDN);
    transpose_kernel<<<GRID1(HIDN * 7), TB, 0, stream>>>(hw2, HW2T, HIDN, 7);

    // ---- CSR build (once) ----
    hipMemsetAsync(cnt, 0, (size_t)NN * 4, stream);
    hist_kernel<<<GRID1(NE), TB, 0, stream>>>(dstI, cnt);
    scan1_kernel<<<NN / 256, 256, 0, stream>>>(cnt, rowp, bsum);
    scan2_kernel<<<1, 256, 0, stream>>>(bsum);
    scan3_kernel<<<NN / 256, 256, 0, stream>>>(rowp, bsum, cursor);
    scatter_kernel<<<GRID1(NE), TB, 0, stream>>>(srcI, dstI, cursor, perm, src_s, dst_s);

    for (int l = 0; l < 2; ++l) {
        transpose_kernel<<<GRID1(HIDN * HIDN), TB, 0, stream>>>(Wq + (size_t)l*HIDN*HIDN, WqT, HIDN, HIDN);
        transpose_kernel<<<GRID1(HIDN * HIDN), TB, 0, stream>>>(Wk + (size_t)l*HIDN*HIDN, WkT, HIDN, HIDN);
        transpose_kernel<<<GRID1(HIDN * HIDN), TB, 0, stream>>>(Wv + (size_t)l*HIDN*HIDN, WvT, HIDN, HIDN);
        transpose_kernel<<<GRID1(EDIM * HIDN), TB, 0, stream>>>(WeK + (size_t)l*EDIM*HIDN, WeKT, EDIM, HIDN);
        transpose_kernel<<<GRID1(EDIM * HIDN), TB, 0, stream>>>(WeV + (size_t)l*EDIM*HIDN, WeVT, EDIM, HIDN);
        transpose_kernel<<<GRID1(HIDN * HIDN), TB, 0, stream>>>(Wo + (size_t)l*HIDN*HIDN, WoT, HIDN, HIDN);
        transpose_kernel<<<GRID1(HIDN * FFN),  TB, 0, stream>>>(fw1 + (size_t)l*HIDN*FFN, W1T, HIDN, FFN);
        transpose_kernel<<<GRID1(FFN * HIDN),  TB, 0, stream>>>(fw2 + (size_t)l*FFN*HIDN, W2T, FFN, HIDN);

        gemm_kernel<0, false><<<dim3(HIDN/128, NN/128), TB, 0, stream>>>(x_b, WqT, nullptr, q_b, NN, HIDN, HIDN, nullptr);
        gemm_kernel<0, false><<<dim3(HIDN/128, NN/128), TB, 0, stream>>>(x_b, WkT, nullptr, k_b, NN, HIDN, HIDN, nullptr);
        gemm_kernel<0, false><<<dim3(HIDN/128, NN/128), TB, 0, stream>>>(x_b, WvT, nullptr, v_b, NN, HIDN, HIDN, nullptr);

        // score phase: per chunk, gathered-row eK GEMM then score (no atomics)
        for (int c = 0; c < NCHUNK; ++c) {
            gemm_kernel<2, false><<<dim3(HIDN/128, NCH/128), TB, 0, stream>>>(
                eattr, WeKT, nullptr, echunk, NCH, HIDN, EDIM, perm + (size_t)c * NCH);
            score_kernel<<<NCH / 4, TB, 0, stream>>>(q_b, k_b, echunk, src_s, dst_s, pbuf, c * NCH);
        }

        // agg phase: q/k dead -> fp32 agg overlays them
        hipMemsetAsync(agg, 0, (size_t)NN * HIDN * 4, stream);
        for (int c = 0; c < NCHUNK; ++c) {
            gemm_kernel<2, false><<<dim3(HIDN/128, NCH/128), TB, 0, stream>>>(
                eattr, WeVT, nullptr, echunk, NCH, HIDN, EDIM, perm + (size_t)c * NCH);
            const int dlo = (c == 0) ? 0 : (c - 1) * DPC;
            const int dhi = (c == NCHUNK - 1) ? NN : (c + 2) * DPC;
            agg_kernel<<<(dhi - dlo) / 4, TB, 0, stream>>>(
                pbuf, v_b, echunk, src_s, rowp, agg, c * NCH, (c + 1) * NCH, dlo);
        }

        gemm_kernel<1, false><<<dim3(HIDN/128, NN/128), TB, 0, stream>>>(agg, WoT, nullptr, tmp_b, NN, HIDN, HIDN, nullptr);
        ln_kernel<<<NN / 4, TB, 0, stream>>>(x_b, tmp_b, c_ln1s + (size_t)l * HIDN, c_ln1b + (size_t)l * HIDN, 0);

        for (int r0 = 0; r0 < NN; r0 += RCH) {
            gemm_kernel<0, true ><<<dim3(FFN/128, RCH/128), TB, 0, stream>>>(
                x_b + (size_t)r0 * HIDN, W1T, c_fb1 + (size_t)l * FFN, hid, RCH, FFN, HIDN, nullptr);
            gemm_kernel<0, false><<<dim3(HIDN/128, RCH/128), TB, 0, stream>>>(
                hid, W2T, c_fb2 + (size_t)l * HIDN, ffnout, RCH, HIDN, FFN, nullptr);
            ln_kernel<<<RCH / 4, TB, 0, stream>>>(x_b, ffnout, c_ln2s + (size_t)l * HIDN, c_ln2b + (size_t)l * HIDN, r0);
        }
    }

    gemm_kernel<0, true><<<dim3(HIDN/128, NACT/128), TB, 0, stream>>>(
        x_b + (size_t)ASTART * HIDN, HW1T, c_hb1, hid, NACT, HIDN, HIDN, nullptr);
    head2_kernel<<<NACT / 4, TB, 0, stream>>>(hid, HW2T, c_hb2, (float*)d_out);
}